// Round 6
// baseline (184.519 us; speedup 1.0000x reference)
//
#include <hip/hip_runtime.h>
#include <hip/hip_bf16.h>

// GCN 2-layer forward, f32.
// Round 5: 4-edge MLP in scatter (independent gather/atomic/store chains),
// scatter blocks dispatched first, aggr64 widened to 16 gathers in flight.

#define N_FEAT_IN 128
#define N_HID 64
#define N_CLS 40

__global__ void k_zero2(int* a, int* b, int n) {
    int i = blockIdx.x * blockDim.x + threadIdx.x;
    if (i < n) { a[i] = 0; b[i] = 0; }
}

__global__ void k_deg_count(const int* __restrict__ ei, int* deg, int E) {
    int e = blockIdx.x * blockDim.x + threadIdx.x;
    if (e < E) atomicAdd(&deg[ei[E + e]], 1);  // dst row
}

// block-inclusive scan of deg + per-block sums; also dinv = 1/sqrt(deg+1)
__global__ void k_scan1(const int* __restrict__ deg, float* __restrict__ dinv,
                        int* incl, int* blksum, int n) {
    __shared__ int s[256];
    int i = blockIdx.x * 256 + threadIdx.x;
    int v = (i < n) ? deg[i] : 0;
    if (i < n) dinv[i] = 1.0f / sqrtf((float)(v + 1));  // +1 = self-loop
    s[threadIdx.x] = v;
    __syncthreads();
    for (int off = 1; off < 256; off <<= 1) {
        int t = (threadIdx.x >= off) ? s[threadIdx.x - off] : 0;
        __syncthreads();
        s[threadIdx.x] += t;
        __syncthreads();
    }
    if (i < n) incl[i] = s[threadIdx.x];
    if (threadIdx.x == 255) blksum[blockIdx.x] = s[255];
}

// single-block parallel scan of block sums (nb <= 256)
__global__ void k_scan2(const int* __restrict__ blksum, int* blkoff, int* row_start,
                        int nb, int n) {
    __shared__ int s[256];
    int t = threadIdx.x;
    int v = (t < nb) ? blksum[t] : 0;
    s[t] = v;
    __syncthreads();
    for (int off = 1; off < 256; off <<= 1) {
        int u = (t >= off) ? s[t - off] : 0;
        __syncthreads();
        s[t] += u;
        __syncthreads();
    }
    if (t < nb) blkoff[t] = s[t] - v;  // exclusive
    if (t == 255) row_start[n] = s[255];  // == E
}

__global__ void k_scan3(const int* __restrict__ incl, const int* __restrict__ deg,
                        const int* __restrict__ blkoff, int* row_start, int n) {
    int i = blockIdx.x * 256 + threadIdx.x;
    if (i < n) row_start[i] = incl[i] - deg[i] + blkoff[blockIdx.x];
}

// ---------- fused: blocks [0,sb) = scatter (4 edges/thread), rest = GEMM1 ----------
__global__ __launch_bounds__(256) void k_g1_scatter(
    const float* __restrict__ x, const float* __restrict__ W,
    const float* __restrict__ dinv, float* __restrict__ hs, int n, int sb,
    const int* __restrict__ ei, const int* __restrict__ row_start,
    int* cursor, int* __restrict__ csr_src, int E) {
    __shared__ float Wl[64 * 64];   // 16 KB (half of W1 per phase)
    __shared__ float Xs[64 * 68];   // 17.4 KB
    int t = threadIdx.x;
    if (blockIdx.x < sb) {
        // scatter: 4 edges per thread, stride-256 within block for coalescing
        int e0 = blockIdx.x * 1024 + t;
        int s[4], d[4], rs[4], off[4];
        bool ok[4];
#pragma unroll
        for (int q = 0; q < 4; ++q) {
            int e = e0 + q * 256;
            ok[q] = (e < E);
            if (ok[q]) { s[q] = ei[e]; d[q] = ei[E + e]; }
        }
#pragma unroll
        for (int q = 0; q < 4; ++q)
            if (ok[q]) rs[q] = row_start[d[q]];
#pragma unroll
        for (int q = 0; q < 4; ++q)
            if (ok[q]) off[q] = atomicAdd(&cursor[d[q]], 1);
#pragma unroll
        for (int q = 0; q < 4; ++q)
            if (ok[q]) csr_src[rs[q] + off[q]] = s[q];
        return;
    }
    int node0 = (blockIdx.x - sb) * 64;
    int tn = t & 15;
    int tc = t >> 4;
    float acc[4][4] = {};
    for (int p = 0; p < 2; ++p) {
#pragma unroll
        for (int i = 0; i < 4; ++i) {
            int r = (t >> 4) + 16 * i;
            int c4 = t & 15;
            *(float4*)&Wl[r * 64 + c4 * 4] =
                *(const float4*)&W[(p * 64 + r) * N_HID + c4 * 4];
            int gr = node0 + r;
            float4 v = (gr < n)
                ? *(const float4*)&x[(size_t)gr * N_FEAT_IN + p * 64 + c4 * 4]
                : make_float4(0.f, 0.f, 0.f, 0.f);
            *(float4*)&Xs[r * 68 + c4 * 4] = v;
        }
        __syncthreads();
        for (int k = 0; k < 64; k += 4) {
            float4 xa[4], wb[4];
#pragma unroll
            for (int i = 0; i < 4; ++i)
                xa[i] = *(float4*)&Xs[(tn + 16 * i) * 68 + k];
#pragma unroll
            for (int kk = 0; kk < 4; ++kk)
                wb[kk] = *(float4*)&Wl[(k + kk) * 64 + tc * 4];
#pragma unroll
            for (int kk = 0; kk < 4; ++kk)
#pragma unroll
                for (int i = 0; i < 4; ++i)
#pragma unroll
                    for (int j = 0; j < 4; ++j)
                        acc[i][j] += ((const float*)&xa[i])[kk] * ((const float*)&wb[kk])[j];
        }
        __syncthreads();
    }
#pragma unroll
    for (int i = 0; i < 4; ++i) {
        int gr = node0 + tn + 16 * i;
        if (gr < n) {
            float di = dinv[gr];
            float4 v = make_float4(acc[i][0] * di, acc[i][1] * di,
                                   acc[i][2] * di, acc[i][3] * di);
            *(float4*)&hs[(size_t)gr * N_HID + tc * 4] = v;
        }
    }
}

// ---------- aggregation, F=64, factorized norm, 16 gathers in flight ----------
// acc = hs[node] + sum_e hs[src_e]     (hs rows pre-scaled by dinv[src])
// L1:  out = relu(dinv[node]*acc + b) * dinv[node]   (pre-scaled for layer 2)
// L2:  out = dinv[node]*acc                          (fed to final GEMM)
template <bool L1>
__global__ __launch_bounds__(256) void k_aggr64(const int* __restrict__ row_start,
                                                const int* __restrict__ csr_src,
                                                const float* __restrict__ dinv,
                                                const float* __restrict__ hs,
                                                const float* __restrict__ b,
                                                float* __restrict__ out, int n) {
    __shared__ int Ss[4 * 64];
    int wv = threadIdx.x >> 6, lane = threadIdx.x & 63;
    int g = lane >> 4, l = lane & 15;
    int node = blockIdx.x * 4 + wv;
    if (node >= n) return;
    float4 acc = make_float4(0.f, 0.f, 0.f, 0.f);
    if (g == 0)  // self-loop term joins the sum with unit weight
        acc = *(const float4*)&hs[(size_t)node * N_HID + l * 4];
    int beg = row_start[node], end = row_start[node + 1];
    for (int j0 = beg; j0 < end; j0 += 64) {
        int j = j0 + lane;
        if (j < end) Ss[wv * 64 + lane] = csr_src[j];
        int cnt = min(64, end - j0);
        int t = 0;
        for (; t + 16 <= cnt; t += 16) {  // 16 edges in flight per wave
            int s1 = Ss[wv * 64 + t + g];
            int s2 = Ss[wv * 64 + t + 4 + g];
            int s3 = Ss[wv * 64 + t + 8 + g];
            int s4 = Ss[wv * 64 + t + 12 + g];
            float4 v1 = *(const float4*)&hs[(size_t)s1 * N_HID + l * 4];
            float4 v2 = *(const float4*)&hs[(size_t)s2 * N_HID + l * 4];
            float4 v3 = *(const float4*)&hs[(size_t)s3 * N_HID + l * 4];
            float4 v4 = *(const float4*)&hs[(size_t)s4 * N_HID + l * 4];
            acc.x += (v1.x + v2.x) + (v3.x + v4.x);
            acc.y += (v1.y + v2.y) + (v3.y + v4.y);
            acc.z += (v1.z + v2.z) + (v3.z + v4.z);
            acc.w += (v1.w + v2.w) + (v3.w + v4.w);
        }
        if (t + 8 <= cnt) {
            int s1 = Ss[wv * 64 + t + g];
            int s2 = Ss[wv * 64 + t + 4 + g];
            float4 v1 = *(const float4*)&hs[(size_t)s1 * N_HID + l * 4];
            float4 v2 = *(const float4*)&hs[(size_t)s2 * N_HID + l * 4];
            acc.x += v1.x + v2.x; acc.y += v1.y + v2.y;
            acc.z += v1.z + v2.z; acc.w += v1.w + v2.w;
            t += 8;
        }
        for (; t < cnt; t += 4) {
            int e = t + g;
            if (e < cnt) {
                int s = Ss[wv * 64 + e];
                float4 v = *(const float4*)&hs[(size_t)s * N_HID + l * 4];
                acc.x += v.x; acc.y += v.y; acc.z += v.z; acc.w += v.w;
            }
        }
    }
    acc.x += __shfl_xor(acc.x, 16); acc.y += __shfl_xor(acc.y, 16);
    acc.z += __shfl_xor(acc.z, 16); acc.w += __shfl_xor(acc.w, 16);
    acc.x += __shfl_xor(acc.x, 32); acc.y += __shfl_xor(acc.y, 32);
    acc.z += __shfl_xor(acc.z, 32); acc.w += __shfl_xor(acc.w, 32);
    if (g == 0) {
        float di = dinv[node];
        float4 o;
        if (L1) {
            float4 bv = *(const float4*)&b[l * 4];
            o.x = fmaxf(di * acc.x + bv.x, 0.f) * di;
            o.y = fmaxf(di * acc.y + bv.y, 0.f) * di;
            o.z = fmaxf(di * acc.z + bv.z, 0.f) * di;
            o.w = fmaxf(di * acc.w + bv.w, 0.f) * di;
        } else {
            o.x = di * acc.x; o.y = di * acc.y;
            o.z = di * acc.z; o.w = di * acc.w;
        }
        *(float4*)&out[(size_t)node * N_HID + l * 4] = o;
    }
}

// ---------- fused final GEMM: out[64n][40] = relu(g2d[64n][64] @ W2 + b2) ----------
__global__ __launch_bounds__(256, 2) void k_gemm2f(const float* __restrict__ g2,
                                                   const float* __restrict__ W,
                                                   const float* __restrict__ bias,
                                                   float* __restrict__ out, int n) {
    __shared__ float Wl[N_HID * N_CLS];   // 10.2 KB
    __shared__ float Xs[64 * 68];         // 17.4 KB
    int t = threadIdx.x;
    int node0 = blockIdx.x * 64;
    for (int i = t * 4; i < N_HID * N_CLS; i += 1024)
        *(float4*)&Wl[i] = *(const float4*)&W[i];
#pragma unroll
    for (int i = 0; i < 4; ++i) {
        int r = (t >> 4) + i * 16;
        int c4 = t & 15;
        int gr = node0 + r;
        float4 v = (gr < n) ? *(const float4*)&g2[(size_t)gr * N_HID + c4 * 4]
                            : make_float4(0.f, 0.f, 0.f, 0.f);
        *(float4*)&Xs[r * 68 + c4 * 4] = v;
    }
    __syncthreads();
    int tn = t & 15;
    int tc = t >> 4;
    if (tc < 10) {
        float acc[4][4] = {};
        for (int k = 0; k < N_HID; k += 4) {
            float4 xa[4], wb[4];
#pragma unroll
            for (int i = 0; i < 4; ++i)
                xa[i] = *(float4*)&Xs[(tn + 16 * i) * 68 + k];
#pragma unroll
            for (int kk = 0; kk < 4; ++kk)
                wb[kk] = *(float4*)&Wl[(k + kk) * N_CLS + tc * 4];
#pragma unroll
            for (int kk = 0; kk < 4; ++kk)
#pragma unroll
                for (int i = 0; i < 4; ++i)
#pragma unroll
                    for (int j = 0; j < 4; ++j)
                        acc[i][j] += ((const float*)&xa[i])[kk] * ((const float*)&wb[kk])[j];
        }
        float4 bv = *(const float4*)&bias[tc * 4];
#pragma unroll
        for (int i = 0; i < 4; ++i) {
            int gr = node0 + tn + 16 * i;
            if (gr < n) {
                float4 v = make_float4(fmaxf(acc[i][0] + bv.x, 0.f),
                                       fmaxf(acc[i][1] + bv.y, 0.f),
                                       fmaxf(acc[i][2] + bv.z, 0.f),
                                       fmaxf(acc[i][3] + bv.w, 0.f));
                *(float4*)&out[(size_t)gr * N_CLS + tc * 4] = v;
            }
        }
    }
}

extern "C" void kernel_launch(void* const* d_in, const int* in_sizes, int n_in,
                              void* d_out, int out_size, void* d_ws, size_t ws_size,
                              hipStream_t stream) {
    const float* x = (const float*)d_in[0];
    const int* ei = (const int*)d_in[1];
    const float* W1 = (const float*)d_in[2];
    const float* b1 = (const float*)d_in[3];
    const float* W2 = (const float*)d_in[4];
    const float* b2 = (const float*)d_in[5];
    float* out = (float*)d_out;

    int n = in_sizes[0] / N_FEAT_IN;  // 50000
    int E = in_sizes[1] / 2;          // 800000
    int nb = (n + 255) / 256;

    char* ws = (char*)d_ws;
    float* dinv      = (float*)(ws + 0);
    int*   deg_i     = (int*)  (ws + 200704);
    int*   row_start = (int*)  (ws + 401408);
    int*   cursor    = (int*)  (ws + 602112);
    int*   incl      = (int*)  (ws + 802816);
    int*   blksum    = (int*)  (ws + 1003520);
    int*   blkoff    = (int*)  (ws + 1004544);
    int*   csr_src   = (int*)  (ws + 1005568);   // E i32
    float* h1s       = (float*)(ws + 7407616);   // n*64 f32; reused as g2d
    float* out1s     = (float*)(ws + 20208128);  // n*64 f32
    float* g2d       = h1s;                      // h1s dead after aggr1

    const int B = 256;
    k_zero2<<<(n + B - 1) / B, B, 0, stream>>>(deg_i, cursor, n);
    k_deg_count<<<(E + B - 1) / B, B, 0, stream>>>(ei, deg_i, E);
    k_scan1<<<nb, 256, 0, stream>>>(deg_i, dinv, incl, blksum, n);
    k_scan2<<<1, 256, 0, stream>>>(blksum, blkoff, row_start, nb, n);
    k_scan3<<<nb, 256, 0, stream>>>(incl, deg_i, blkoff, row_start, n);

    int gb = (n + 63) / 64;
    int sb = (E + 1023) / 1024;
    k_g1_scatter<<<sb + gb, 256, 0, stream>>>(x, W1, dinv, h1s, n, sb,
                                              ei, row_start, cursor, csr_src, E);

    k_aggr64<true><<<(n + 3) / 4, 256, 0, stream>>>(row_start, csr_src, dinv,
                                                    h1s, b1, out1s, n);
    k_aggr64<false><<<(n + 3) / 4, 256, 0, stream>>>(row_start, csr_src, dinv,
                                                     out1s, nullptr, g2d, n);
    k_gemm2f<<<gb, 256, 0, stream>>>(g2d, W2, b2, out, n);
}

// Round 7
// 143.827 us; speedup vs baseline: 1.2829x; 1.2829x over previous
//
#include <hip/hip_runtime.h>
#include <hip/hip_bf16.h>

// GCN 2-layer forward, f32.
// Round 6 (corrected): rank-from-histogram CSR build. k_count records
// rank[e] = atomicAdd(deg[d],1). After scans, scatter is ATOMIC-FREE and
// fused behind GEMM1 (GEMM blocks first, round-4 ordering). Cursor deleted.

#define N_FEAT_IN 128
#define N_HID 64
#define N_CLS 40

__global__ void k_zero(int* a, int n) {
    int i = blockIdx.x * blockDim.x + threadIdx.x;
    if (i < n) a[i] = 0;
}

__global__ void k_count(const int* __restrict__ ei, int* deg, int* __restrict__ rank,
                        int E) {
    int e = blockIdx.x * blockDim.x + threadIdx.x;
    if (e < E) rank[e] = atomicAdd(&deg[ei[E + e]], 1);
}

__global__ void k_scan1(const int* __restrict__ deg, float* __restrict__ dinv,
                        int* incl, int* blksum, int n) {
    __shared__ int s[256];
    int i = blockIdx.x * 256 + threadIdx.x;
    int v = (i < n) ? deg[i] : 0;
    if (i < n) dinv[i] = 1.0f / sqrtf((float)(v + 1));  // +1 = self-loop
    s[threadIdx.x] = v;
    __syncthreads();
    for (int off = 1; off < 256; off <<= 1) {
        int t = (threadIdx.x >= off) ? s[threadIdx.x - off] : 0;
        __syncthreads();
        s[threadIdx.x] += t;
        __syncthreads();
    }
    if (i < n) incl[i] = s[threadIdx.x];
    if (threadIdx.x == 255) blksum[blockIdx.x] = s[255];
}

__global__ void k_scan2(const int* __restrict__ blksum, int* blkoff, int* row_start,
                        int nb, int n) {
    __shared__ int s[256];
    int t = threadIdx.x;
    int v = (t < nb) ? blksum[t] : 0;
    s[t] = v;
    __syncthreads();
    for (int off = 1; off < 256; off <<= 1) {
        int u = (t >= off) ? s[t - off] : 0;
        __syncthreads();
        s[t] += u;
        __syncthreads();
    }
    if (t < nb) blkoff[t] = s[t] - v;  // exclusive
    if (t == 255) row_start[n] = s[255];  // == E
}

__global__ void k_scan3(const int* __restrict__ incl, const int* __restrict__ deg,
                        const int* __restrict__ blkoff, int* row_start, int n) {
    int i = blockIdx.x * 256 + threadIdx.x;
    if (i < n) row_start[i] = incl[i] - deg[i] + blkoff[blockIdx.x];
}

// ---------- fused: blocks [0,gb) = GEMM1 (h1s = (x@W1)*dinv),
//                   blocks [gb,..) = atomic-free scatter ----------
__global__ __launch_bounds__(256) void k_g1_scatter2(
    const float* __restrict__ x, const float* __restrict__ W,
    const float* __restrict__ dinv, float* __restrict__ hs, int n, int gb,
    const int* __restrict__ ei, const int* __restrict__ rank,
    const int* __restrict__ row_start, int* __restrict__ csr_src, int E) {
    __shared__ float Wl[64 * 64];   // 16 KB
    __shared__ float Xs[64 * 68];   // 17.4 KB
    int t = threadIdx.x;
    if (blockIdx.x >= gb) {
        int e = (blockIdx.x - gb) * 256 + t;
        if (e < E) {
            int s = ei[e];
            int d = ei[E + e];
            csr_src[row_start[d] + rank[e]] = s;  // no atomic
        }
        return;
    }
    int node0 = blockIdx.x * 64;
    int tn = t & 15;
    int tc = t >> 4;
    float acc[4][4] = {};
    for (int p = 0; p < 2; ++p) {
#pragma unroll
        for (int i = 0; i < 4; ++i) {
            int r = (t >> 4) + 16 * i;
            int c4 = t & 15;
            *(float4*)&Wl[r * 64 + c4 * 4] =
                *(const float4*)&W[(p * 64 + r) * N_HID + c4 * 4];
            int gr = node0 + r;
            float4 v = (gr < n)
                ? *(const float4*)&x[(size_t)gr * N_FEAT_IN + p * 64 + c4 * 4]
                : make_float4(0.f, 0.f, 0.f, 0.f);
            *(float4*)&Xs[r * 68 + c4 * 4] = v;
        }
        __syncthreads();
        for (int k = 0; k < 64; k += 4) {
            float4 xa[4], wb[4];
#pragma unroll
            for (int i = 0; i < 4; ++i)
                xa[i] = *(float4*)&Xs[(tn + 16 * i) * 68 + k];
#pragma unroll
            for (int kk = 0; kk < 4; ++kk)
                wb[kk] = *(float4*)&Wl[(k + kk) * 64 + tc * 4];
#pragma unroll
            for (int kk = 0; kk < 4; ++kk)
#pragma unroll
                for (int i = 0; i < 4; ++i)
#pragma unroll
                    for (int j = 0; j < 4; ++j)
                        acc[i][j] += ((const float*)&xa[i])[kk] * ((const float*)&wb[kk])[j];
        }
        __syncthreads();
    }
#pragma unroll
    for (int i = 0; i < 4; ++i) {
        int gr = node0 + tn + 16 * i;
        if (gr < n) {
            float di = dinv[gr];
            float4 v = make_float4(acc[i][0] * di, acc[i][1] * di,
                                   acc[i][2] * di, acc[i][3] * di);
            *(float4*)&hs[(size_t)gr * N_HID + tc * 4] = v;
        }
    }
}

// ---------- aggregation, F=64, factorized norm, 16 gathers in flight ----------
template <bool L1>
__global__ __launch_bounds__(256) void k_aggr64(const int* __restrict__ row_start,
                                                const int* __restrict__ csr_src,
                                                const float* __restrict__ dinv,
                                                const float* __restrict__ hs,
                                                const float* __restrict__ b,
                                                float* __restrict__ out, int n) {
    __shared__ int Ss[4 * 64];
    int wv = threadIdx.x >> 6, lane = threadIdx.x & 63;
    int g = lane >> 4, l = lane & 15;
    int node = blockIdx.x * 4 + wv;
    if (node >= n) return;
    float4 acc = make_float4(0.f, 0.f, 0.f, 0.f);
    if (g == 0)
        acc = *(const float4*)&hs[(size_t)node * N_HID + l * 4];
    int beg = row_start[node], end = row_start[node + 1];
    for (int j0 = beg; j0 < end; j0 += 64) {
        int j = j0 + lane;
        if (j < end) Ss[wv * 64 + lane] = csr_src[j];
        int cnt = min(64, end - j0);
        int t = 0;
        for (; t + 16 <= cnt; t += 16) {
            int s1 = Ss[wv * 64 + t + g];
            int s2 = Ss[wv * 64 + t + 4 + g];
            int s3 = Ss[wv * 64 + t + 8 + g];
            int s4 = Ss[wv * 64 + t + 12 + g];
            float4 v1 = *(const float4*)&hs[(size_t)s1 * N_HID + l * 4];
            float4 v2 = *(const float4*)&hs[(size_t)s2 * N_HID + l * 4];
            float4 v3 = *(const float4*)&hs[(size_t)s3 * N_HID + l * 4];
            float4 v4 = *(const float4*)&hs[(size_t)s4 * N_HID + l * 4];
            acc.x += (v1.x + v2.x) + (v3.x + v4.x);
            acc.y += (v1.y + v2.y) + (v3.y + v4.y);
            acc.z += (v1.z + v2.z) + (v3.z + v4.z);
            acc.w += (v1.w + v2.w) + (v3.w + v4.w);
        }
        if (t + 8 <= cnt) {
            int s1 = Ss[wv * 64 + t + g];
            int s2 = Ss[wv * 64 + t + 4 + g];
            float4 v1 = *(const float4*)&hs[(size_t)s1 * N_HID + l * 4];
            float4 v2 = *(const float4*)&hs[(size_t)s2 * N_HID + l * 4];
            acc.x += v1.x + v2.x; acc.y += v1.y + v2.y;
            acc.z += v1.z + v2.z; acc.w += v1.w + v2.w;
            t += 8;
        }
        for (; t < cnt; t += 4) {
            int e = t + g;
            if (e < cnt) {
                int s = Ss[wv * 64 + e];
                float4 v = *(const float4*)&hs[(size_t)s * N_HID + l * 4];
                acc.x += v.x; acc.y += v.y; acc.z += v.z; acc.w += v.w;
            }
        }
    }
    acc.x += __shfl_xor(acc.x, 16); acc.y += __shfl_xor(acc.y, 16);
    acc.z += __shfl_xor(acc.z, 16); acc.w += __shfl_xor(acc.w, 16);
    acc.x += __shfl_xor(acc.x, 32); acc.y += __shfl_xor(acc.y, 32);
    acc.z += __shfl_xor(acc.z, 32); acc.w += __shfl_xor(acc.w, 32);
    if (g == 0) {
        float di = dinv[node];
        float4 o;
        if (L1) {
            float4 bv = *(const float4*)&b[l * 4];
            o.x = fmaxf(di * acc.x + bv.x, 0.f) * di;
            o.y = fmaxf(di * acc.y + bv.y, 0.f) * di;
            o.z = fmaxf(di * acc.z + bv.z, 0.f) * di;
            o.w = fmaxf(di * acc.w + bv.w, 0.f) * di;
        } else {
            o.x = di * acc.x; o.y = di * acc.y;
            o.z = di * acc.z; o.w = di * acc.w;
        }
        *(float4*)&out[(size_t)node * N_HID + l * 4] = o;
    }
}

// ---------- fused final GEMM: out[64n][40] = relu(g2d[64n][64] @ W2 + b2) ----------
__global__ __launch_bounds__(256, 2) void k_gemm2f(const float* __restrict__ g2,
                                                   const float* __restrict__ W,
                                                   const float* __restrict__ bias,
                                                   float* __restrict__ out, int n) {
    __shared__ float Wl[N_HID * N_CLS];
    __shared__ float Xs[64 * 68];
    int t = threadIdx.x;
    int node0 = blockIdx.x * 64;
    for (int i = t * 4; i < N_HID * N_CLS; i += 1024)
        *(float4*)&Wl[i] = *(const float4*)&W[i];
#pragma unroll
    for (int i = 0; i < 4; ++i) {
        int r = (t >> 4) + i * 16;
        int c4 = t & 15;
        int gr = node0 + r;
        float4 v = (gr < n) ? *(const float4*)&g2[(size_t)gr * N_HID + c4 * 4]
                            : make_float4(0.f, 0.f, 0.f, 0.f);
        *(float4*)&Xs[r * 68 + c4 * 4] = v;
    }
    __syncthreads();
    int tn = t & 15;
    int tc = t >> 4;
    if (tc < 10) {
        float acc[4][4] = {};
        for (int k = 0; k < N_HID; k += 4) {
            float4 xa[4], wb[4];
#pragma unroll
            for (int i = 0; i < 4; ++i)
                xa[i] = *(float4*)&Xs[(tn + 16 * i) * 68 + k];
#pragma unroll
            for (int kk = 0; kk < 4; ++kk)
                wb[kk] = *(float4*)&Wl[(k + kk) * N_CLS + tc * 4];
#pragma unroll
            for (int kk = 0; kk < 4; ++kk)
#pragma unroll
                for (int i = 0; i < 4; ++i)
#pragma unroll
                    for (int j = 0; j < 4; ++j)
                        acc[i][j] += ((const float*)&xa[i])[kk] * ((const float*)&wb[kk])[j];
        }
        float4 bv = *(const float4*)&bias[tc * 4];
#pragma unroll
        for (int i = 0; i < 4; ++i) {
            int gr = node0 + tn + 16 * i;
            if (gr < n) {
                float4 v = make_float4(fmaxf(acc[i][0] + bv.x, 0.f),
                                       fmaxf(acc[i][1] + bv.y, 0.f),
                                       fmaxf(acc[i][2] + bv.z, 0.f),
                                       fmaxf(acc[i][3] + bv.w, 0.f));
                *(float4*)&out[(size_t)gr * N_CLS + tc * 4] = v;
            }
        }
    }
}

extern "C" void kernel_launch(void* const* d_in, const int* in_sizes, int n_in,
                              void* d_out, int out_size, void* d_ws, size_t ws_size,
                              hipStream_t stream) {
    const float* x = (const float*)d_in[0];
    const int* ei = (const int*)d_in[1];
    const float* W1 = (const float*)d_in[2];
    const float* b1 = (const float*)d_in[3];
    const float* W2 = (const float*)d_in[4];
    const float* b2 = (const float*)d_in[5];
    float* out = (float*)d_out;

    int n = in_sizes[0] / N_FEAT_IN;  // 50000
    int E = in_sizes[1] / 2;          // 800000
    int nb = (n + 255) / 256;

    char* ws = (char*)d_ws;
    float* dinv      = (float*)(ws + 0);         // n f32
    int*   deg_i     = (int*)  (ws + 200704);    // n i32
    int*   row_start = (int*)  (ws + 401408);    // n+1 i32
    int*   incl      = (int*)  (ws + 602112);    // n i32
    int*   blksum    = (int*)  (ws + 802816);    // nb i32
    int*   blkoff    = (int*)  (ws + 803840);    // nb i32
    int*   rank      = (int*)  (ws + 804864);    // E i32
    int*   csr_src   = (int*)  (ws + 4004864);   // E i32
    float* h1s       = (float*)(ws + 7204864);   // n*64 f32; reused as g2d
    float* out1s     = (float*)(ws + 20004864);  // n*64 f32
    float* g2d       = h1s;

    const int B = 256;
    int gb = (n + 63) / 64;
    int cb = (E + 255) / 256;

    k_zero<<<(n + B - 1) / B, B, 0, stream>>>(deg_i, n);
    k_count<<<cb, B, 0, stream>>>(ei, deg_i, rank, E);
    k_scan1<<<nb, 256, 0, stream>>>(deg_i, dinv, incl, blksum, n);
    k_scan2<<<1, 256, 0, stream>>>(blksum, blkoff, row_start, nb, n);
    k_scan3<<<nb, 256, 0, stream>>>(incl, deg_i, blkoff, row_start, n);

    // GEMM1 (needs dinv, ready now) fused with atomic-free scatter
    k_g1_scatter2<<<gb + cb, 256, 0, stream>>>(x, W1, dinv, h1s, n, gb,
                                               ei, rank, row_start, csr_src, E);

    k_aggr64<true><<<(n + 3) / 4, 256, 0, stream>>>(row_start, csr_src, dinv,
                                                    h1s, b1, out1s, n);
    k_aggr64<false><<<(n + 3) / 4, 256, 0, stream>>>(row_start, csr_src, dinv,
                                                     out1s, nullptr, g2d, n);
    k_gemm2f<<<gb, 256, 0, stream>>>(g2d, W2, b2, out, n);
}